// Round 1
// baseline (2911.658 us; speedup 1.0000x reference)
//
#include <hip/hip_runtime.h>
#include <hip/hip_bf16.h>
#include <stdint.h>

// Problem constants
#define NN 100000   // nodes
#define RR 200      // relations
#define DD 200      // dim
#define BB 30       // bases
#define LL 2        // layers
#define EE 800000   // edges

// Padded GEMM geometry
#define KP 224      // K padded to 7 chunks of 32
#define NP 208      // N padded to 13 frags of 16
#define XP 208      // xb row pitch (bf16 elems), 416B = 26 x 16B
#define AP 232      // LDS A-tile pitch (bf16 elems) -> 464B, 2-way-free banks
#define TE 64       // edges per tile
#define MAXTILES 12700  // E/TE + RR upper bound on sum ceil(E_r/TE)

using bf16x8 = __attribute__((ext_vector_type(8))) short;
using f32x4  = __attribute__((ext_vector_type(4))) float;

// Workspace byte offsets (all 16B-aligned)
#define OFF_NORM  0u          // E floats            = 3,200,000
#define OFF_SORT  3200000u    // E ints              = 3,200,000
#define OFF_CNT   6400000u    // 4KB counters: relCount@0, relStart@256, relCursor@512, tileOff@768 (int idx)
#define OFF_XB    6404096u    // N*XP bf16           = 41,600,000  (deg8 20MB aliases here transiently)
#define OFF_WT    48004096u   // R*NP*KP bf16        = 18,636,800
#define OFF_ROOTT 66640896u   // NP*KP bf16          = 93,184
// total ~66.8 MB

static __device__ __forceinline__ short f2bf(float v) {
    union { __hip_bfloat16 h; short s; } u;
    u.h = __float2bfloat16(v);
    return u.s;
}

// ---- Stage A: degree counts + relation histogram ----
__global__ void kCount(const int* __restrict__ ei, const int* __restrict__ et,
                       unsigned int* __restrict__ deg8, int* __restrict__ cnt) {
    int e = blockIdx.x * 256 + threadIdx.x;
    if (e >= EE) return;
    int d = ei[EE + e];
    int t = et[e];
    int comb = d * RR + t;                      // < 20M, fits int
    atomicAdd(&deg8[comb >> 2], 1u << ((comb & 3) * 8));
    atomicAdd(&cnt[t], 1);
}

// ---- Stage A: tiny exclusive scans (edges and tiles) ----
__global__ void kScan(int* __restrict__ cnt) {
    __shared__ int c[RR];
    int tid = threadIdx.x;
    for (int r = tid; r < RR; r += 64) c[r] = cnt[r];
    __syncthreads();
    if (tid == 0) {
        int s = 0, ts = 0;
        #pragma unroll 8
        for (int r = 0; r < RR; ++r) {
            cnt[256 + r] = s;   // relStart
            cnt[512 + r] = s;   // relCursor
            cnt[768 + r] = ts;  // tileOff
            s += c[r];
            ts += (c[r] + TE - 1) / TE;
        }
        cnt[256 + RR] = s;
        cnt[768 + RR] = ts;
    }
}

// ---- Stage A: per-edge norm + counting-sort scatter by relation ----
__global__ void kNormScatter(const int* __restrict__ ei, const int* __restrict__ et,
                             const unsigned int* __restrict__ deg8, int* __restrict__ cnt,
                             float* __restrict__ norm, int* __restrict__ sortedE) {
    int e = blockIdx.x * 256 + threadIdx.x;
    if (e >= EE) return;
    int d = ei[EE + e];
    int t = et[e];
    int comb = d * RR + t;
    unsigned int deg = (deg8[comb >> 2] >> ((comb & 3) * 8)) & 0xffu;
    norm[e] = 1.0f / (float)(deg ? deg : 1u);
    int pos = atomicAdd(&cnt[512 + t], 1);
    sortedE[pos] = e;
}

// ---- fp32 [N,DD] -> bf16 [N,XP] (optionally fused relu) ----
__global__ void kConvert(const float* __restrict__ x, short* __restrict__ xb, int doRelu) {
    int idx = blockIdx.x * 256 + threadIdx.x;
    if (idx >= NN * XP) return;
    int i = idx / XP, col = idx - i * XP;
    float v = 0.0f;
    if (col < DD) {
        v = x[i * DD + col];
        if (doRelu) v = fmaxf(v, 0.0f);
    }
    xb[idx] = (col < DD) ? f2bf(v) : (short)0;
}

// ---- relu in place on d_out (final layer) ----
__global__ void kRelu(float* __restrict__ y) {
    int idx = blockIdx.x * 256 + threadIdx.x;
    if (idx < NN * DD) y[idx] = fmaxf(y[idx], 0.0f);
}

// ---- Per-layer: Wt[r][n][k] = sum_b comp[r][b]*bases[b][k][n], bf16, zero-padded ----
__global__ void kW(const float* __restrict__ comp, const float* __restrict__ bases,
                   short* __restrict__ Wt) {
    __shared__ float compS[BB];
    __shared__ short wt[32 * 209];   // [kk][n], pitch 209 to spread banks on transpose read
    int kt = blockIdx.x;             // 0..6
    int r  = blockIdx.y;             // 0..199
    int tid = threadIdx.x;
    if (tid < BB) compS[tid] = comp[r * BB + tid];
    __syncthreads();
    for (int idx = tid; idx < 32 * NP; idx += 256) {
        int kk = idx / NP, n = idx - kk * NP;
        int k = kt * 32 + kk;
        float v = 0.0f;
        if (k < DD && n < DD) {
            const float* bp = bases + k * DD + n;
            #pragma unroll
            for (int b = 0; b < BB; ++b) v += compS[b] * bp[b * DD * DD];
        }
        wt[kk * 209 + n] = f2bf(v);
    }
    __syncthreads();
    for (int idx = tid; idx < NP * 32; idx += 256) {
        int n = idx / 32, kk = idx - n * 32;
        Wt[((size_t)r * NP + n) * KP + kt * 32 + kk] = wt[kk * 209 + n];
    }
}

// ---- Per-layer: rootT[n][k] = root[k][n], bf16, zero-padded ----
__global__ void kRootT(const float* __restrict__ root, short* __restrict__ rootT) {
    int idx = blockIdx.x * 256 + threadIdx.x;
    if (idx >= NP * KP) return;
    int n = idx / KP, k = idx - n * KP;
    rootT[idx] = (n < DD && k < DD) ? f2bf(root[k * DD + n]) : (short)0;
}

// ---- Per-layer: y[i][:] = xb[i][:] @ root + bias  (dense MFMA, no atomics) ----
__global__ __launch_bounds__(256) void kRootGemm(const short* __restrict__ xb,
        const short* __restrict__ rootT, const float* __restrict__ bias,
        float* __restrict__ y) {
    __shared__ short As[TE * AP];
    int i0 = blockIdx.x * TE;
    int tid = threadIdx.x;
    int rowL = tid >> 2, sub = tid & 3;
    int i = i0 + rowL;
    for (int c = sub; c < 29; c += 4) {
        int4 v = make_int4(0, 0, 0, 0);
        if (i < NN && c < 26) v = *(const int4*)(xb + i * XP + c * 8);
        *(int4*)(&As[rowL * AP + c * 8]) = v;
    }
    __syncthreads();
    int lane = tid & 63, wave = tid >> 6;
    int stripe = wave * 16;
    int arow = stripe + (lane & 15);
    int kg = (lane >> 4) * 8;
    f32x4 acc[13];
    #pragma unroll
    for (int f = 0; f < 13; ++f) acc[f] = (f32x4){0.f, 0.f, 0.f, 0.f};
    const short* bBase = rootT + (lane & 15) * KP + kg;
    #pragma unroll 1
    for (int kc = 0; kc < 7; ++kc) {
        bf16x8 a = *(const bf16x8*)(&As[arow * AP + kc * 32 + kg]);
        #pragma unroll
        for (int f = 0; f < 13; ++f) {
            bf16x8 b = *(const bf16x8*)(bBase + f * 16 * KP + kc * 32);
            acc[f] = __builtin_amdgcn_mfma_f32_16x16x32_bf16(a, b, acc[f], 0, 0, 0);
        }
    }
    int colLane = lane & 15;
    int rbase = i0 + stripe + (lane >> 4) * 4;
    #pragma unroll
    for (int f = 0; f < 13; ++f) {
        int col = f * 16 + colLane;
        if (col < DD) {
            float bv = bias[col];
            #pragma unroll
            for (int j = 0; j < 4; ++j) {
                int row = rbase + j;
                if (row < NN) y[row * DD + col] = acc[f][j] + bv;
            }
        }
    }
}

// ---- Per-layer: per-(relation, 64-edge-tile) gather-GEMM-scatter ----
__global__ __launch_bounds__(256) void kMsg(const int* __restrict__ ei,
        const short* __restrict__ xb, const short* __restrict__ Wt,
        const int* __restrict__ cnt, const int* __restrict__ sortedE,
        const float* __restrict__ norm, float* __restrict__ y) {
    __shared__ short As[TE * AP];
    __shared__ int dstS[TE];
    __shared__ float normS[TE];
    const int* tileOff  = cnt + 768;
    const int* relStart = cnt + 256;
    int bid = blockIdx.x;
    if (bid >= tileOff[RR]) return;
    // binary search: largest r with tileOff[r] <= bid
    int lo = 0, hi = RR;
    while (hi - lo > 1) {
        int mid = (lo + hi) >> 1;
        if (tileOff[mid] <= bid) lo = mid; else hi = mid;
    }
    int r = lo, tile = bid - tileOff[r];
    int eBase = relStart[r] + tile * TE;
    int eEnd  = relStart[r + 1];
    int tid = threadIdx.x;
    int rowL = tid >> 2, sub = tid & 3;
    int eIdx = eBase + rowL;
    bool valid = eIdx < eEnd;
    int eid = valid ? sortedE[eIdx] : 0;
    if (sub == 0) {
        dstS[rowL]  = valid ? ei[EE + eid] : 0;
        normS[rowL] = valid ? norm[eid] : 0.0f;
    }
    int srcRow = valid ? ei[eid] : 0;
    for (int c = sub; c < 29; c += 4) {
        int4 v = make_int4(0, 0, 0, 0);
        if (valid && c < 26) v = *(const int4*)(xb + srcRow * XP + c * 8);
        *(int4*)(&As[rowL * AP + c * 8]) = v;
    }
    __syncthreads();
    int lane = tid & 63, wave = tid >> 6;
    int stripe = wave * 16;
    int arow = stripe + (lane & 15);
    int kg = (lane >> 4) * 8;
    f32x4 acc[13];
    #pragma unroll
    for (int f = 0; f < 13; ++f) acc[f] = (f32x4){0.f, 0.f, 0.f, 0.f};
    const short* bBase = Wt + (size_t)r * (NP * KP) + (lane & 15) * KP + kg;
    #pragma unroll 1
    for (int kc = 0; kc < 7; ++kc) {
        bf16x8 a = *(const bf16x8*)(&As[arow * AP + kc * 32 + kg]);
        #pragma unroll
        for (int f = 0; f < 13; ++f) {
            bf16x8 b = *(const bf16x8*)(bBase + f * 16 * KP + kc * 32);
            acc[f] = __builtin_amdgcn_mfma_f32_16x16x32_bf16(a, b, acc[f], 0, 0, 0);
        }
    }
    int colLane = lane & 15;
    int rL0 = stripe + (lane >> 4) * 4;
    #pragma unroll
    for (int f = 0; f < 13; ++f) {
        int col = f * 16 + colLane;
        if (col < DD) {
            #pragma unroll
            for (int j = 0; j < 4; ++j) {
                int rl = rL0 + j;
                float nm = normS[rl];
                if (nm != 0.0f) atomicAdd(&y[dstS[rl] * DD + col], acc[f][j] * nm);
            }
        }
    }
}

extern "C" void kernel_launch(void* const* d_in, const int* in_sizes, int n_in,
                              void* d_out, int out_size, void* d_ws, size_t ws_size,
                              hipStream_t stream) {
    (void)in_sizes; (void)n_in; (void)out_size; (void)ws_size;
    const int*   ei    = (const int*)d_in[0];
    const int*   et    = (const int*)d_in[1];
    const float* emb   = (const float*)d_in[2];
    const float* comp  = (const float*)d_in[3];
    const float* bases = (const float*)d_in[4];
    const float* root  = (const float*)d_in[5];
    const float* bias  = (const float*)d_in[6];
    float* y = (float*)d_out;
    char* ws = (char*)d_ws;
    float* norm   = (float*)(ws + OFF_NORM);
    int*   sortedE= (int*)(ws + OFF_SORT);
    int*   cnt    = (int*)(ws + OFF_CNT);
    short* xb     = (short*)(ws + OFF_XB);
    short* Wt     = (short*)(ws + OFF_WT);
    short* rootT  = (short*)(ws + OFF_ROOTT);
    unsigned int* deg8 = (unsigned int*)(ws + OFF_XB);  // 20MB transient alias

    hipMemsetAsync(deg8, 0, (size_t)NN * RR, stream);
    hipMemsetAsync(cnt, 0, 4096, stream);
    kCount<<<(EE + 255) / 256, 256, 0, stream>>>(ei, et, deg8, cnt);
    kScan<<<1, 64, 0, stream>>>(cnt);
    kNormScatter<<<(EE + 255) / 256, 256, 0, stream>>>(ei, et, deg8, cnt, norm, sortedE);
    kConvert<<<(NN * XP + 255) / 256, 256, 0, stream>>>(emb, xb, 0);

    for (int l = 0; l < LL; ++l) {
        kW<<<dim3(7, RR), 256, 0, stream>>>(comp + l * RR * BB,
                                            bases + (size_t)l * BB * DD * DD, Wt);
        kRootT<<<(NP * KP + 255) / 256, 256, 0, stream>>>(root + l * DD * DD, rootT);
        kRootGemm<<<(NN + TE - 1) / TE, 256, 0, stream>>>(xb, rootT, bias + l * DD, y);
        kMsg<<<MAXTILES, 256, 0, stream>>>(ei, xb, Wt, cnt, sortedE, norm, y);
        if (l == 0) {
            kConvert<<<(NN * XP + 255) / 256, 256, 0, stream>>>(y, xb, 1);
        } else {
            kRelu<<<(NN * DD + 255) / 256, 256, 0, stream>>>(y);
        }
    }
}